// Round 3
// baseline (57.268 us; speedup 1.0000x reference)
//
#include <hip/hip_runtime.h>

// Problem constants (B,C,H,W = 8,1,88,128; TIMESTEPS=1000)
static constexpr int N       = 8 * 1 * 88 * 128;   // 90112 pixels
static constexpr int VEC     = 4;
static constexpr int NV      = N / VEC;            // 22528 float4 pairs
static constexpr int THREADS = 256;
static constexpr int BLOCKS  = NV / THREADS;       // 88 blocks, exact fit

// Module-scope accumulators (NOT d_ws: the harness unconditionally re-poisons
// the 256 MiB workspace with a ~40.5 us fillBufferAligned every iteration —
// rocprof rounds 0-2 — so d_ws forces poison-robust protocols for nothing).
// g_M accumulates the global mismatch count; g_count is the arrival counter
// for the last-block-done pattern. The last block resets both to 0 so the
// captured graph can replay; the dispatch boundary publishes the reset.
__device__ unsigned g_M     = 0;
__device__ unsigned g_count = 0;

// idx(x) = int(max(x*1000 - 1, 0)); _rn intrinsics forbid FMA contraction so
// quantization boundaries bit-match numpy's mul-then-sub (absmax was 0.0).
__device__ __forceinline__ int bucket(float x) {
    float v = __fsub_rn(__fmul_rn(x, 1000.0f), 1.0f);
    v = fmaxf(v, 0.0f);
    return (int)v;   // truncation toward zero == astype(int32) for v >= 0
}

// Single dispatch, last-block-done, zero spin:
//   - 88 blocks spread the 720 KB of HBM-cold reads over 88 CUs.
//   - Each block: integer partial -> relaxed atomicAdd into g_M, then
//     acq_rel arrival on g_count. The acquire in the final arrival
//     synchronizes-with every other block's release, making all g_M adds
//     visible (cross-XCD safe: device/agent-scope atomics).
//   - The LAST block to arrive (old == BLOCKS-1) is the reducer: by
//     definition nobody is still publishing, so it never waits. It reads
//     g_M, writes loss = M*(1/(N*999) + 1/N) in fp64, and resets globals.
__global__ __launch_bounds__(THREADS) void loss_kernel(
        const float4* __restrict__ r, const float4* __restrict__ t,
        float* __restrict__ out) {
    const int i = blockIdx.x * THREADS + threadIdx.x;   // 0..NV-1, exact
    const float4 rv = r[i];
    const float4 tv = t[i];
    int c = (bucket(rv.x) != bucket(tv.x))
          + (bucket(rv.y) != bucket(tv.y))
          + (bucket(rv.z) != bucket(tv.z))
          + (bucket(rv.w) != bucket(tv.w));
    // wave (64-lane) shuffle reduction
    #pragma unroll
    for (int off = 32; off > 0; off >>= 1)
        c += __shfl_down(c, off, 64);
    __shared__ int smem[THREADS / 64];
    if ((threadIdx.x & 63) == 0) smem[threadIdx.x >> 6] = c;
    __syncthreads();
    if (threadIdx.x == 0) {
        const unsigned partial = (unsigned)(smem[0] + smem[1] + smem[2] + smem[3]);
        __hip_atomic_fetch_add(&g_M, partial,
                               __ATOMIC_RELAXED, __HIP_MEMORY_SCOPE_AGENT);
        const unsigned old = __hip_atomic_fetch_add(&g_count, 1u,
                               __ATOMIC_ACQ_REL, __HIP_MEMORY_SCOPE_AGENT);
        if (old == BLOCKS - 1) {
            const unsigned M = __hip_atomic_load(&g_M,
                               __ATOMIC_RELAXED, __HIP_MEMORY_SCOPE_AGENT);
            const double invN = 1.0 / (double)N;
            out[0] = (float)((double)M * (invN / 999.0 + invN));
            // reset for the next graph replay (visible via dispatch boundary)
            __hip_atomic_store(&g_M, 0u,
                               __ATOMIC_RELAXED, __HIP_MEMORY_SCOPE_AGENT);
            __hip_atomic_store(&g_count, 0u,
                               __ATOMIC_RELAXED, __HIP_MEMORY_SCOPE_AGENT);
        }
    }
}

extern "C" void kernel_launch(void* const* d_in, const int* in_sizes, int n_in,
                              void* d_out, int out_size, void* d_ws, size_t ws_size,
                              hipStream_t stream) {
    const float4* r = (const float4*)d_in[0];  // reconstructed_image, fp32
    const float4* t = (const float4*)d_in[1];  // target_image, fp32
    float* out = (float*)d_out;                // scalar fp32 loss
    (void)d_ws; (void)ws_size;                 // workspace intentionally unused

    loss_kernel<<<BLOCKS, THREADS, 0, stream>>>(r, t, out);
}

// Round 4
// 55.196 us; speedup vs baseline: 1.0375x; 1.0375x over previous
//
#include <hip/hip_runtime.h>

// Problem constants (B,C,H,W = 8,1,88,128; TIMESTEPS=1000)
static constexpr int N       = 8 * 1 * 88 * 128;   // 90112 pixels
static constexpr int VEC     = 4;
static constexpr int NV      = N / VEC;            // 22528 float4 pairs
static constexpr int THREADS = 256;
static constexpr int BLOCKS  = NV / THREADS;       // 88 blocks, exact fit

// Single module-scope atomic word: bits [19:0] = running mismatch sum
// (M <= 90112 < 2^20), bits [20+] = arrival count (<= 88). The payload
// travels INSIDE the atomic, so relaxed ordering suffices — the location's
// total modification order guarantees the last arriver's returned value
// contains all 87 other partials. No fences, no second dispatch, no spin.
// (R3 post-mortem: two atomics + acq_rel per block from 8 XCDs cost more
// than the dispatch boundary they replaced. This is one relaxed atomic.)
// NOT d_ws: the harness unconditionally re-poisons the 256 MiB workspace
// (~40 us fillBufferAligned, 83% of HBM peak) inside the timed region.
static constexpr unsigned ARRIVE = 1u << 20;
__device__ unsigned g_packed = 0;

// idx(x) = int(max(x*1000 - 1, 0)); _rn intrinsics forbid FMA contraction so
// quantization boundaries bit-match numpy's mul-then-sub (absmax was 0.0).
__device__ __forceinline__ int bucket(float x) {
    float v = __fsub_rn(__fmul_rn(x, 1000.0f), 1.0f);
    v = fmaxf(v, 0.0f);
    return (int)v;   // truncation toward zero == astype(int32) for v >= 0
}

__global__ __launch_bounds__(THREADS) void loss_kernel(
        const float4* __restrict__ r, const float4* __restrict__ t,
        float* __restrict__ out) {
    const int i = blockIdx.x * THREADS + threadIdx.x;   // 0..NV-1, exact
    const float4 rv = r[i];
    const float4 tv = t[i];
    int c = (bucket(rv.x) != bucket(tv.x))
          + (bucket(rv.y) != bucket(tv.y))
          + (bucket(rv.z) != bucket(tv.z))
          + (bucket(rv.w) != bucket(tv.w));
    // wave (64-lane) shuffle reduction
    #pragma unroll
    for (int off = 32; off > 0; off >>= 1)
        c += __shfl_down(c, off, 64);
    __shared__ int smem[THREADS / 64];
    if ((threadIdx.x & 63) == 0) smem[threadIdx.x >> 6] = c;
    __syncthreads();
    if (threadIdx.x == 0) {
        const unsigned partial = (unsigned)(smem[0] + smem[1] + smem[2] + smem[3]);
        const unsigned old = __hip_atomic_fetch_add(&g_packed, ARRIVE | partial,
                               __ATOMIC_RELAXED, __HIP_MEMORY_SCOPE_AGENT);
        if ((old >> 20) == BLOCKS - 1) {            // we are the last arriver
            const unsigned M = (old & (ARRIVE - 1)) + partial;
            const double invN = 1.0 / (double)N;
            out[0] = (float)((double)M * (invN / 999.0 + invN));
            // reset for next graph replay; same thread + same location ->
            // coherence orders this after our fetch_add, and the kernel
            // boundary publishes it device-wide before the next dispatch.
            __hip_atomic_store(&g_packed, 0u,
                               __ATOMIC_RELAXED, __HIP_MEMORY_SCOPE_AGENT);
        }
    }
}

extern "C" void kernel_launch(void* const* d_in, const int* in_sizes, int n_in,
                              void* d_out, int out_size, void* d_ws, size_t ws_size,
                              hipStream_t stream) {
    const float4* r = (const float4*)d_in[0];  // reconstructed_image, fp32
    const float4* t = (const float4*)d_in[1];  // target_image, fp32
    float* out = (float*)d_out;                // scalar fp32 loss
    (void)d_ws; (void)ws_size;                 // workspace intentionally unused

    loss_kernel<<<BLOCKS, THREADS, 0, stream>>>(r, t, out);
}